// Round 2
// baseline (6203.464 us; speedup 1.0000x reference)
//
#include <hip/hip_runtime.h>
#include <math.h>

// Problem constants (b=2, n=4096, k=32, d0=64, d1=16, L=2, rh=16, HEADS=4)
#define BB    2
#define NN    4096
#define KK    32
#define D0    64
#define D1    16
#define D13   48      // d1*3
#define RHD   16
#define NHEAD 4
#define NLAYER 2
#define EPS   1e-6f
#define SCALE 0.18898223650461363f   // 1/sqrt(16 + 12)

__device__ __forceinline__ float wred(float v) {
    #pragma unroll
    for (int o = 32; o > 0; o >>= 1) v += __shfl_xor(v, o, 64);
    return v;
}

__device__ __forceinline__ float gelu_t(float x) {
    // jax.nn.gelu default (approximate=True, tanh form)
    float x3 = x * x * x;
    return 0.5f * x * (1.0f + tanhf(0.7978845608028654f * (x + 0.044715f * x3)));
}

// ---------------- geometry: rel, dist, rhat ----------------
__global__ void geom_kernel(const float* __restrict__ coords,
                            const int* __restrict__ nbr,
                            float* __restrict__ rhat,
                            float* __restrict__ dist) {
    int e = blockIdx.x * blockDim.x + threadIdx.x;
    if (e >= BB * NN * KK) return;
    int bn = e / KK;          // b*NN + i
    int bb = bn / NN;
    int j  = nbr[e];
    const float* cs = coords + (size_t)bn * 3;
    const float* cn = coords + ((size_t)bb * NN + j) * 3;
    float rx = cn[0] - cs[0], ry = cn[1] - cs[1], rz = cn[2] - cs[2];
    float d  = sqrtf(rx * rx + ry * ry + rz * rz);
    float iv = 1.0f / (d + EPS);
    rhat[e * 3 + 0] = rx * iv;
    rhat[e * 3 + 1] = ry * iv;
    rhat[e * 3 + 2] = rz * iv;
    dist[e] = d;
}

// ---------------- prenorm: g0 = LN(f0), g1 = RMS(f1) ----------------
__global__ __launch_bounds__(64) void prenorm_kernel(const float* __restrict__ f0,
                                                     const float* __restrict__ f1,
                                                     float* __restrict__ g0,
                                                     float* __restrict__ g1) {
    int node = blockIdx.x;
    int lane = threadIdx.x;
    float x  = f0[(size_t)node * D0 + lane];
    float mu = wred(x) * (1.0f / D0);
    float dv = x - mu;
    float var = wred(dv * dv) * (1.0f / D0);
    g0[(size_t)node * D0 + lane] = dv * rsqrtf(var + EPS);

    float w = (lane < D13) ? f1[(size_t)node * D13 + lane] : 0.0f;
    float t = wred(w * w);
    float rms = rsqrtf(t * (1.0f / D1) + EPS);
    if (lane < D13) g1[(size_t)node * D13 + lane] = w * rms;
}

// ---------------- fused attention (one block per node) ----------------
// Thread mapping for the heavy projections:
//   wave g = tid>>6 owns neighbors j in [g*8, g*8+8)
//   lane e = tid&63 owns output channel e; weights are loaded coalesced
//   once per wave and reused across the 8 neighbors (register tiling).
//   Neighbor activations come from LDS as same-address broadcasts.
__global__ __launch_bounds__(256, 4) void attn_kernel(
    const float* __restrict__ g0g, const float* __restrict__ g1g,
    const int* __restrict__ nbr_idx,
    const float* __restrict__ rhatg, const float* __restrict__ distg,
    const float* __restrict__ Wq0, const float* __restrict__ Wq1,
    const float* __restrict__ Wk00, const float* __restrict__ Wk10,
    const float* __restrict__ Wk01, const float* __restrict__ Wk11,
    const float* __restrict__ Wk11r,
    const float* __restrict__ Wv00, const float* __restrict__ Wv10,
    const float* __restrict__ Wv01, const float* __restrict__ Wv11,
    const float* __restrict__ Wv11r,
    const float* __restrict__ Rw1, const float* __restrict__ Rb1,
    const float* __restrict__ Rw20, const float* __restrict__ Rw21,
    const float* __restrict__ Wo0, const float* __restrict__ Wo1,
    float* __restrict__ f0b, float* __restrict__ f1b) {

    int node = blockIdx.x;
    int bb   = node / NN;
    int tid  = threadIdx.x;
    int lane = tid & 63;
    int g    = tid >> 6;      // wave id 0..3

    __shared__ float g0s[D0], g1s[D13], q0s[D0], q1s[D13];
    __shared__ int   nbrs[KK];
    __shared__ float dsts[KK], rhts[KK * 3];
    __shared__ float h0s[KK][D0];     // gathered neighbor g0
    __shared__ float h1s[KK][D13];    // gathered neighbor g1
    __shared__ float d1s[KK][D1];     // dot1
    __shared__ float rhfs[KK][RHD];   // radial hidden
    __shared__ float v0s[KK][D0];
    __shared__ float v1s[KK][D13];
    __shared__ float lgs0[KK][NHEAD]; // q0.k0 part
    __shared__ float lgs1[KK][NHEAD]; // q1.k1 part
    __shared__ float o0s[D0], o1s[D13];

    // ---- P0: load own-node data + neighbor meta ----
    if (tid < 64)       g0s[tid] = g0g[(size_t)node * D0 + tid];
    else if (tid < 112) g1s[tid - 64] = g1g[(size_t)node * D13 + (tid - 64)];
    else if (tid < 144) nbrs[tid - 112] = nbr_idx[(size_t)node * KK + (tid - 112)];
    else if (tid < 176) dsts[tid - 144] = distg[(size_t)node * KK + (tid - 144)];
    if (tid < 96) rhts[tid] = rhatg[(size_t)node * 96 + tid];
    __syncthreads();

    // ---- P1: q projections + neighbor gather ----
    if (tid < 64) {
        float acc = 0.0f;
        #pragma unroll
        for (int c = 0; c < D0; c++) acc += g0s[c] * Wq0[c * D0 + tid];
        q0s[tid] = acc;
    } else if (tid < 112) {
        int idx = tid - 64, e = idx / 3, m = idx % 3;
        float acc = 0.0f;
        #pragma unroll
        for (int c = 0; c < D1; c++) acc += g1s[c * 3 + m] * Wq1[c * D1 + e];
        q1s[idx] = acc;
    }
    for (int t = tid; t < KK * (D0 + D13); t += 256) {
        if (t < KK * D0) {
            int j = t >> 6, c = t & 63;
            h0s[j][c] = g0g[((size_t)bb * NN + nbrs[j]) * D0 + c];
        } else {
            int t2 = t - KK * D0;
            int j = t2 / D13, c = t2 % D13;
            h1s[j][c] = g1g[((size_t)bb * NN + nbrs[j]) * D13 + c];
        }
    }
    __syncthreads();

    // ---- P2a: dot1 and radial hidden ----
    for (int t = tid; t < 2 * KK * D1; t += 256) {
        if (t < KK * D1) {
            int j = t >> 4, c = t & 15;
            d1s[j][c] = h1s[j][c * 3 + 0] * rhts[j * 3 + 0]
                      + h1s[j][c * 3 + 1] * rhts[j * 3 + 1]
                      + h1s[j][c * 3 + 2] * rhts[j * 3 + 2];
        } else {
            int t2 = t - KK * D1;
            int j = t2 >> 4, u = t2 & 15;
            rhfs[j][u] = gelu_t(dsts[j] * Rw1[u] + Rb1[u]);
        }
    }
    __syncthreads();

    // ---- P2b: k0/v0 register-tiled: thread = (e=lane, 8 neighbors of wave g)
    {
        int j0 = g * 8;
        float ak[8], av[8];
        #pragma unroll
        for (int jj = 0; jj < 8; jj++) { ak[jj] = 0.0f; av[jj] = 0.0f; }
        #pragma unroll 4
        for (int c = 0; c < D0; c++) {
            float wk = Wk00[c * D0 + lane];   // coalesced, reused x8
            float wv = Wv00[c * D0 + lane];
            #pragma unroll
            for (int jj = 0; jj < 8; jj++) {
                float h = h0s[j0 + jj][c];    // LDS broadcast
                ak[jj] += h * wk;
                av[jj] += h * wv;
            }
        }
        #pragma unroll
        for (int c = 0; c < D1; c++) {
            float wk = Wk10[c * D0 + lane];
            float wv = Wv10[c * D0 + lane];
            #pragma unroll
            for (int jj = 0; jj < 8; jj++) {
                float dd = d1s[j0 + jj][c];
                ak[jj] += dd * wk;
                av[jj] += dd * wv;
            }
        }
        // r0 per (j, e)
        float ru[RHD];
        #pragma unroll
        for (int u = 0; u < RHD; u++) ru[u] = Rw20[u * D0 + lane];
        float q0e = q0s[lane];
        #pragma unroll
        for (int jj = 0; jj < 8; jj++) {
            int j = j0 + jj;
            float r0 = 0.0f;
            #pragma unroll
            for (int u = 0; u < RHD; u++) r0 += rhfs[j][u] * ru[u];
            float k0 = ak[jj] * r0;
            v0s[j][lane] = av[jj] * r0;
            // logit contribution: reduce q0[e]*k0 over the 16 lanes of head e>>4
            float lc = q0e * k0;
            lc += __shfl_xor(lc, 1, 16);
            lc += __shfl_xor(lc, 2, 16);
            lc += __shfl_xor(lc, 4, 16);
            lc += __shfl_xor(lc, 8, 16);
            if ((lane & 15) == 0) lgs0[j][lane >> 4] = lc;
        }
    }

    // ---- P2c: k1/v1 register-tiled: thread = (e1 = tid&15, 2 neighbors)
    {
        int e1 = tid & 15;
        int g2 = tid >> 4;          // 0..15, 2 neighbors each
        int gs = (g2 & 3);          // stagger group within wave
        float ru1[RHD];
        #pragma unroll
        for (int u = 0; u < RHD; u++) ru1[u] = Rw21[u * D1 + e1];
        #pragma unroll
        for (int jj = 0; jj < 2; jj++) {
            int j = g2 * 2 + jj;
            float r1 = 0.0f;
            #pragma unroll
            for (int u = 0; u < RHD; u++) r1 += rhfs[j][u] * ru1[u];
            // scalar->d1 parts (h0 @ Wk01/Wv01), staggered c to dodge bank aliasing
            float a01k = 0.0f, a01v = 0.0f;
            #pragma unroll
            for (int cc = 0; cc < D0; cc++) {
                int c = (cc + gs * 16) & 63;
                float h = h0s[j][c];
                a01k += h * Wk01[c * D1 + e1];
                a01v += h * Wv01[c * D1 + e1];
            }
            float a11k = 0.0f, a11v = 0.0f;
            #pragma unroll
            for (int cc = 0; cc < D1; cc++) {
                int c = (cc + gs * 4) & 15;
                float dd = d1s[j][c];
                a11k += dd * Wk11r[c * D1 + e1];
                a11v += dd * Wv11r[c * D1 + e1];
            }
            float sk = a01k + a11k, sv = a01v + a11v;
            float lc = 0.0f;
            #pragma unroll
            for (int m = 0; m < 3; m++) {
                float hk = 0.0f, hv = 0.0f;
                #pragma unroll
                for (int cc = 0; cc < D1; cc++) {
                    int c = (cc + gs * 4) & 15;
                    float h1v = h1s[j][c * 3 + m];
                    hk += h1v * Wk11[c * D1 + e1];
                    hv += h1v * Wv11[c * D1 + e1];
                }
                float rh_m = rhts[j * 3 + m];
                float k1 = (sk * rh_m + hk) * r1;
                float v1 = (sv * rh_m + hv) * r1;
                v1s[j][e1 * 3 + m] = v1;
                lc += q1s[e1 * 3 + m] * k1;
            }
            // reduce over the 4 lanes of head e1>>2
            lc += __shfl_xor(lc, 1, 4);
            lc += __shfl_xor(lc, 2, 4);
            if ((e1 & 3) == 0) lgs1[j][e1 >> 2] = lc;
        }
    }
    __syncthreads();

    // ---- P3: softmax over neighbors per head ----
    if (tid < NHEAD) {
        int h = tid;
        float l[KK];
        float mx = -1e30f;
        #pragma unroll
        for (int j = 0; j < KK; j++) {
            l[j] = (lgs0[j][h] + lgs1[j][h]) * SCALE;
            mx = fmaxf(mx, l[j]);
        }
        float s = 0.0f;
        #pragma unroll
        for (int j = 0; j < KK; j++) {
            float ex = expf(l[j] - mx);
            l[j] = ex;
            s += ex;
        }
        float iv = 1.0f / s;
        #pragma unroll
        for (int j = 0; j < KK; j++) lgs0[j][h] = l[j] * iv;
    }
    __syncthreads();

    // ---- P4: attention-weighted sums ----
    if (tid < 64) {
        int e = tid, h = e >> 4;
        float acc = 0.0f;
        #pragma unroll
        for (int j = 0; j < KK; j++) acc += lgs0[j][h] * v0s[j][e];
        o0s[e] = acc;
    } else if (tid < 112) {
        int idx = tid - 64, e = idx / 3, m = idx % 3, h = e >> 2;
        float acc = 0.0f;
        #pragma unroll
        for (int j = 0; j < KK; j++) acc += lgs0[j][h] * v1s[j][e * 3 + m];
        o1s[idx] = acc;
    }
    __syncthreads();

    // ---- P5: output projection + residual ----
    if (tid < 64) {
        int c = tid;
        float acc = 0.0f;
        #pragma unroll
        for (int e = 0; e < D0; e++) acc += o0s[e] * Wo0[e * D0 + c];
        f0b[(size_t)node * D0 + c] += acc;
    } else if (tid < 112) {
        int idx = tid - 64, f = idx / 3, m = idx % 3;
        float acc = 0.0f;
        #pragma unroll
        for (int c = 0; c < D1; c++) acc += o1s[c * 3 + m] * Wo1[c * D1 + f];
        f1b[(size_t)node * D13 + idx] += acc;
    }
}

// ---------------- fused FFN (prenorm + MLPs + gate) ----------------
__global__ __launch_bounds__(256) void ffn_kernel(
    const float* __restrict__ F0w1, const float* __restrict__ F0w2,
    const float* __restrict__ F1w1, const float* __restrict__ F1w2,
    float* __restrict__ f0b, float* __restrict__ f1b) {

    int node = blockIdx.x;
    int tid  = threadIdx.x;
    __shared__ float g0s[D0], g1s[D13], ts[256], us[D13 * 4];  // us: 64 x 3

    if (tid < 64) {
        float x  = f0b[(size_t)node * D0 + tid];
        float mu = wred(x) * (1.0f / D0);
        float dv = x - mu;
        float var = wred(dv * dv) * (1.0f / D0);
        g0s[tid] = dv * rsqrtf(var + EPS);
    } else if (tid < 128) {
        int lane = tid - 64;
        float w = (lane < D13) ? f1b[(size_t)node * D13 + lane] : 0.0f;
        float t = wred(w * w);
        float rms = rsqrtf(t * (1.0f / D1) + EPS);
        if (lane < D13) g1s[lane] = w * rms;
    }
    __syncthreads();

    {   // hidden layer of scalar FFN (d0 -> 4*d0 = 256)
        float acc = 0.0f;
        #pragma unroll
        for (int c = 0; c < D0; c++) acc += g0s[c] * F0w1[c * 256 + tid];
        ts[tid] = gelu_t(acc);
    }
    if (tid < 192) {  // u1 = g1 @ F1w1 : (d1,3) -> (64,3)
        int e = tid / 3, m = tid % 3;
        float acc = 0.0f;
        #pragma unroll
        for (int c = 0; c < D1; c++) acc += g1s[c * 3 + m] * F1w1[c * 64 + e];
        us[tid] = acc;
    }
    __syncthreads();

    if (tid < 64) {  // gate
        int e = tid;
        float a = us[e * 3], b = us[e * 3 + 1], c = us[e * 3 + 2];
        float nrm = sqrtf(a * a + b * b + c * c);
        float gate = 1.0f / (1.0f + expf(-nrm));
        us[e * 3 + 0] *= gate;
        us[e * 3 + 1] *= gate;
        us[e * 3 + 2] *= gate;
    }
    __syncthreads();

    if (tid < 64) {
        int c = tid;
        float acc = 0.0f;
        #pragma unroll
        for (int j = 0; j < 256; j++) acc += ts[j] * F0w2[j * D0 + c];
        f0b[(size_t)node * D0 + c] += acc;
    } else if (tid < 112) {
        int idx = tid - 64, f = idx / 3, m = idx % 3;
        float acc = 0.0f;
        #pragma unroll
        for (int e = 0; e < 64; e++) acc += us[e * 3 + m] * F1w2[e * D1 + f];
        f1b[(size_t)node * D13 + idx] += acc;
    }
}

// ---------------- final concat ----------------
__global__ void concat_kernel(const float* __restrict__ f0b,
                              const float* __restrict__ f1b,
                              float* __restrict__ out) {
    int i = blockIdx.x * blockDim.x + threadIdx.x;
    if (i >= BB * NN * (D0 + D13)) return;
    int node = i / (D0 + D13), c = i % (D0 + D13);
    out[i] = (c < D0) ? f0b[(size_t)node * D0 + c]
                      : f1b[(size_t)node * D13 + (c - D0)];
}

extern "C" void kernel_launch(void* const* d_in, const int* in_sizes, int n_in,
                              void* d_out, int out_size, void* d_ws, size_t ws_size,
                              hipStream_t stream) {
    const float* f0     = (const float*)d_in[0];
    const float* f1     = (const float*)d_in[1];
    const float* coords = (const float*)d_in[2];
    const int*   nbr    = (const int*)d_in[3];
    const float* Wq0    = (const float*)d_in[4];
    const float* Wq1    = (const float*)d_in[5];
    const float* Wk00   = (const float*)d_in[6];
    const float* Wk10   = (const float*)d_in[7];
    const float* Wk01   = (const float*)d_in[8];
    const float* Wk11   = (const float*)d_in[9];
    const float* Wk11r  = (const float*)d_in[10];
    const float* Wv00   = (const float*)d_in[11];
    const float* Wv10   = (const float*)d_in[12];
    const float* Wv01   = (const float*)d_in[13];
    const float* Wv11   = (const float*)d_in[14];
    const float* Wv11r  = (const float*)d_in[15];
    const float* Rw1    = (const float*)d_in[16];
    const float* Rb1    = (const float*)d_in[17];
    const float* Rw20   = (const float*)d_in[18];
    const float* Rw21   = (const float*)d_in[19];
    const float* Wo0    = (const float*)d_in[20];
    const float* Wo1    = (const float*)d_in[21];
    const float* F0w1   = (const float*)d_in[22];
    const float* F0w2   = (const float*)d_in[23];
    const float* F1w1   = (const float*)d_in[24];
    const float* F1w2   = (const float*)d_in[25];
    float* out = (float*)d_out;

    // workspace layout
    float* ws    = (float*)d_ws;
    float* f0b   = ws;                 ws += (size_t)BB * NN * D0;
    float* f1b   = ws;                 ws += (size_t)BB * NN * D13;
    float* g0b   = ws;                 ws += (size_t)BB * NN * D0;
    float* g1b   = ws;                 ws += (size_t)BB * NN * D13;
    float* rhatb = ws;                 ws += (size_t)BB * NN * KK * 3;
    float* distb = ws;                 ws += (size_t)BB * NN * KK;

    int nodes = BB * NN;
    int edges = BB * NN * KK;

    geom_kernel<<<(edges + 255) / 256, 256, 0, stream>>>(coords, nbr, rhatb, distb);
    hipMemcpyAsync(f0b, f0, (size_t)nodes * D0 * sizeof(float),
                   hipMemcpyDeviceToDevice, stream);
    hipMemcpyAsync(f1b, f1, (size_t)nodes * D13 * sizeof(float),
                   hipMemcpyDeviceToDevice, stream);

    for (int l = 0; l < NLAYER; l++) {
        prenorm_kernel<<<nodes, 64, 0, stream>>>(f0b, f1b, g0b, g1b);
        attn_kernel<<<nodes, 256, 0, stream>>>(
            g0b, g1b, nbr, rhatb, distb,
            Wq0 + l * D0 * D0, Wq1 + l * D1 * D1,
            Wk00 + l * D0 * D0, Wk10 + l * D1 * D0,
            Wk01 + l * D0 * D1, Wk11 + l * D1 * D1, Wk11r + l * D1 * D1,
            Wv00 + l * D0 * D0, Wv10 + l * D1 * D0,
            Wv01 + l * D0 * D1, Wv11 + l * D1 * D1, Wv11r + l * D1 * D1,
            Rw1 + l * RHD, Rb1 + l * RHD,
            Rw20 + l * RHD * D0, Rw21 + l * RHD * D1,
            Wo0 + l * D0 * D0, Wo1 + l * D1 * D1,
            f0b, f1b);
        ffn_kernel<<<nodes, 256, 0, stream>>>(
            F0w1 + l * D0 * 256, F0w2 + l * 256 * D0,
            F1w1 + l * D1 * 64, F1w2 + l * 64 * D1,
            f0b, f1b);
    }

    concat_kernel<<<(nodes * (D0 + D13) + 255) / 256, 256, 0, stream>>>(f0b, f1b, out);
}

// Round 3
// 1626.984 us; speedup vs baseline: 3.8129x; 3.8129x over previous
//
#include <hip/hip_runtime.h>
#include <math.h>

// Problem constants (b=2, n=4096, k=32, d0=64, d1=16, L=2, rh=16, HEADS=4)
#define BB    2
#define NN    4096
#define KK    32
#define D0    64
#define D1    16
#define D13   48      // d1*3
#define RHD   16
#define NHEAD 4
#define NLAYER 2
#define EPS   1e-6f
#define SCALE 0.18898223650461363f   // 1/sqrt(16 + 12)

__device__ __forceinline__ float wred(float v) {
    #pragma unroll
    for (int o = 32; o > 0; o >>= 1) v += __shfl_xor(v, o, 64);
    return v;
}

__device__ __forceinline__ float gelu_t(float x) {
    // jax.nn.gelu default (approximate=True, tanh form)
    float x3 = x * x * x;
    return 0.5f * x * (1.0f + tanhf(0.7978845608028654f * (x + 0.044715f * x3)));
}

// ---------------- geometry: rel, dist, rhat ----------------
__global__ void geom_kernel(const float* __restrict__ coords,
                            const int* __restrict__ nbr,
                            float* __restrict__ rhat,
                            float* __restrict__ dist) {
    int e = blockIdx.x * blockDim.x + threadIdx.x;
    if (e >= BB * NN * KK) return;
    int bn = e / KK;          // b*NN + i
    int bb = bn / NN;
    int j  = nbr[e];
    const float* cs = coords + (size_t)bn * 3;
    const float* cn = coords + ((size_t)bb * NN + j) * 3;
    float rx = cn[0] - cs[0], ry = cn[1] - cs[1], rz = cn[2] - cs[2];
    float d  = sqrtf(rx * rx + ry * ry + rz * rz);
    float iv = 1.0f / (d + EPS);
    rhat[e * 3 + 0] = rx * iv;
    rhat[e * 3 + 1] = ry * iv;
    rhat[e * 3 + 2] = rz * iv;
    dist[e] = d;
}

// ---------------- prenorm: g0 = LN(f0), g1 = RMS(f1) ----------------
__global__ __launch_bounds__(64) void prenorm_kernel(const float* __restrict__ f0,
                                                     const float* __restrict__ f1,
                                                     float* __restrict__ g0,
                                                     float* __restrict__ g1) {
    int node = blockIdx.x;
    int lane = threadIdx.x;
    float x  = f0[(size_t)node * D0 + lane];
    float mu = wred(x) * (1.0f / D0);
    float dv = x - mu;
    float var = wred(dv * dv) * (1.0f / D0);
    g0[(size_t)node * D0 + lane] = dv * rsqrtf(var + EPS);

    float w = (lane < D13) ? f1[(size_t)node * D13 + lane] : 0.0f;
    float t = wred(w * w);
    float rms = rsqrtf(t * (1.0f / D1) + EPS);
    if (lane < D13) g1[(size_t)node * D13 + lane] = w * rms;
}

// ---------------- fused attention (one block per node) ----------------
// Register tiling: wave g owns neighbors [g*8, g*8+8); lane e owns output
// channel e. Weights loaded coalesced once per wave, reused x8 from registers;
// neighbor activations come from LDS as same-address broadcasts.
// NOTE: no occupancy floor in launch_bounds — R2 showed __launch_bounds__(256,4)
// caps VGPR at 64 and spills GBs to scratch (FETCH 2.7GB, WRITE 4.9GB).
__global__ __launch_bounds__(256) void attn_kernel(
    const float* __restrict__ g0g, const float* __restrict__ g1g,
    const int* __restrict__ nbr_idx,
    const float* __restrict__ rhatg, const float* __restrict__ distg,
    const float* __restrict__ Wq0, const float* __restrict__ Wq1,
    const float* __restrict__ Wk00, const float* __restrict__ Wk10,
    const float* __restrict__ Wk01, const float* __restrict__ Wk11,
    const float* __restrict__ Wk11r,
    const float* __restrict__ Wv00, const float* __restrict__ Wv10,
    const float* __restrict__ Wv01, const float* __restrict__ Wv11,
    const float* __restrict__ Wv11r,
    const float* __restrict__ Rw1, const float* __restrict__ Rb1,
    const float* __restrict__ Rw20, const float* __restrict__ Rw21,
    const float* __restrict__ Wo0, const float* __restrict__ Wo1,
    float* __restrict__ f0b, float* __restrict__ f1b) {

    int node = blockIdx.x;
    int bb   = node / NN;
    int tid  = threadIdx.x;
    int lane = tid & 63;
    int g    = tid >> 6;      // wave id 0..3

    __shared__ float g0s[D0], g1s[D13], q0s[D0], q1s[D13];
    __shared__ int   nbrs[KK];
    __shared__ float dsts[KK], rhts[KK * 3];
    __shared__ float h0s[KK][D0];     // gathered neighbor g0
    __shared__ float h1s[KK][D13];    // gathered neighbor g1
    __shared__ float d1s[KK][D1];     // dot1
    __shared__ float rhfs[KK][RHD];   // radial hidden
    __shared__ float v0s[KK][D0];
    __shared__ float v1s[KK][D13];
    __shared__ float lgs0[KK][NHEAD]; // q0.k0 part
    __shared__ float lgs1[KK][NHEAD]; // q1.k1 part
    __shared__ float o0s[D0], o1s[D13];

    // ---- P0: load own-node data + neighbor meta ----
    if (tid < 64)       g0s[tid] = g0g[(size_t)node * D0 + tid];
    else if (tid < 112) g1s[tid - 64] = g1g[(size_t)node * D13 + (tid - 64)];
    else if (tid < 144) nbrs[tid - 112] = nbr_idx[(size_t)node * KK + (tid - 112)];
    else if (tid < 176) dsts[tid - 144] = distg[(size_t)node * KK + (tid - 144)];
    if (tid < 96) rhts[tid] = rhatg[(size_t)node * 96 + tid];
    __syncthreads();

    // ---- P1: q projections + neighbor gather ----
    if (tid < 64) {
        float acc = 0.0f;
        #pragma unroll
        for (int c = 0; c < D0; c++) acc += g0s[c] * Wq0[c * D0 + tid];
        q0s[tid] = acc;
    } else if (tid < 112) {
        int idx = tid - 64, e = idx / 3, m = idx % 3;
        float acc = 0.0f;
        #pragma unroll
        for (int c = 0; c < D1; c++) acc += g1s[c * 3 + m] * Wq1[c * D1 + e];
        q1s[idx] = acc;
    }
    for (int t = tid; t < KK * (D0 + D13); t += 256) {
        if (t < KK * D0) {
            int j = t >> 6, c = t & 63;
            h0s[j][c] = g0g[((size_t)bb * NN + nbrs[j]) * D0 + c];
        } else {
            int t2 = t - KK * D0;
            int j = t2 / D13, c = t2 % D13;
            h1s[j][c] = g1g[((size_t)bb * NN + nbrs[j]) * D13 + c];
        }
    }
    __syncthreads();

    // ---- P2a: dot1 and radial hidden ----
    for (int t = tid; t < 2 * KK * D1; t += 256) {
        if (t < KK * D1) {
            int j = t >> 4, c = t & 15;
            d1s[j][c] = h1s[j][c * 3 + 0] * rhts[j * 3 + 0]
                      + h1s[j][c * 3 + 1] * rhts[j * 3 + 1]
                      + h1s[j][c * 3 + 2] * rhts[j * 3 + 2];
        } else {
            int t2 = t - KK * D1;
            int j = t2 >> 4, u = t2 & 15;
            rhfs[j][u] = gelu_t(dsts[j] * Rw1[u] + Rb1[u]);
        }
    }
    __syncthreads();

    // ---- P2b: k0/v0 register-tiled: thread = (e=lane, 8 neighbors of wave g)
    {
        int j0 = g * 8;
        float ak[8], av[8];
        #pragma unroll
        for (int jj = 0; jj < 8; jj++) { ak[jj] = 0.0f; av[jj] = 0.0f; }
        #pragma unroll 4
        for (int c = 0; c < D0; c++) {
            float wk = Wk00[c * D0 + lane];   // coalesced, reused x8
            float wv = Wv00[c * D0 + lane];
            #pragma unroll
            for (int jj = 0; jj < 8; jj++) {
                float h = h0s[j0 + jj][c];    // LDS broadcast
                ak[jj] += h * wk;
                av[jj] += h * wv;
            }
        }
        #pragma unroll
        for (int c = 0; c < D1; c++) {
            float wk = Wk10[c * D0 + lane];
            float wv = Wv10[c * D0 + lane];
            #pragma unroll
            for (int jj = 0; jj < 8; jj++) {
                float dd = d1s[j0 + jj][c];
                ak[jj] += dd * wk;
                av[jj] += dd * wv;
            }
        }
        // r0 per (j, e)
        float ru[RHD];
        #pragma unroll
        for (int u = 0; u < RHD; u++) ru[u] = Rw20[u * D0 + lane];
        float q0e = q0s[lane];
        #pragma unroll
        for (int jj = 0; jj < 8; jj++) {
            int j = j0 + jj;
            float r0 = 0.0f;
            #pragma unroll
            for (int u = 0; u < RHD; u++) r0 += rhfs[j][u] * ru[u];
            float k0 = ak[jj] * r0;
            v0s[j][lane] = av[jj] * r0;
            // logit contribution: reduce q0[e]*k0 over the 16 lanes of head e>>4
            float lc = q0e * k0;
            lc += __shfl_xor(lc, 1, 16);
            lc += __shfl_xor(lc, 2, 16);
            lc += __shfl_xor(lc, 4, 16);
            lc += __shfl_xor(lc, 8, 16);
            if ((lane & 15) == 0) lgs0[j][lane >> 4] = lc;
        }
    }

    // ---- P2c: k1/v1 register-tiled: thread = (e1 = tid&15, 2 neighbors)
    {
        int e1 = tid & 15;
        int g2 = tid >> 4;          // 0..15, 2 neighbors each
        int gs = (g2 & 3);          // stagger group within wave
        float ru1[RHD];
        #pragma unroll
        for (int u = 0; u < RHD; u++) ru1[u] = Rw21[u * D1 + e1];
        #pragma unroll
        for (int jj = 0; jj < 2; jj++) {
            int j = g2 * 2 + jj;
            float r1 = 0.0f;
            #pragma unroll
            for (int u = 0; u < RHD; u++) r1 += rhfs[j][u] * ru1[u];
            // scalar->d1 parts (h0 @ Wk01/Wv01), staggered c to dodge bank aliasing
            float a01k = 0.0f, a01v = 0.0f;
            #pragma unroll
            for (int cc = 0; cc < D0; cc++) {
                int c = (cc + gs * 16) & 63;
                float h = h0s[j][c];
                a01k += h * Wk01[c * D1 + e1];
                a01v += h * Wv01[c * D1 + e1];
            }
            float a11k = 0.0f, a11v = 0.0f;
            #pragma unroll
            for (int cc = 0; cc < D1; cc++) {
                int c = (cc + gs * 4) & 15;
                float dd = d1s[j][c];
                a11k += dd * Wk11r[c * D1 + e1];
                a11v += dd * Wv11r[c * D1 + e1];
            }
            float sk = a01k + a11k, sv = a01v + a11v;
            float lc = 0.0f;
            #pragma unroll
            for (int m = 0; m < 3; m++) {
                float hk = 0.0f, hv = 0.0f;
                #pragma unroll
                for (int cc = 0; cc < D1; cc++) {
                    int c = (cc + gs * 4) & 15;
                    float h1v = h1s[j][c * 3 + m];
                    hk += h1v * Wk11[c * D1 + e1];
                    hv += h1v * Wv11[c * D1 + e1];
                }
                float rh_m = rhts[j * 3 + m];
                float k1 = (sk * rh_m + hk) * r1;
                float v1 = (sv * rh_m + hv) * r1;
                v1s[j][e1 * 3 + m] = v1;
                lc += q1s[e1 * 3 + m] * k1;
            }
            // reduce over the 4 lanes of head e1>>2
            lc += __shfl_xor(lc, 1, 4);
            lc += __shfl_xor(lc, 2, 4);
            if ((e1 & 3) == 0) lgs1[j][e1 >> 2] = lc;
        }
    }
    __syncthreads();

    // ---- P3: softmax over neighbors per head ----
    if (tid < NHEAD) {
        int h = tid;
        float l[KK];
        float mx = -1e30f;
        #pragma unroll
        for (int j = 0; j < KK; j++) {
            l[j] = (lgs0[j][h] + lgs1[j][h]) * SCALE;
            mx = fmaxf(mx, l[j]);
        }
        float s = 0.0f;
        #pragma unroll
        for (int j = 0; j < KK; j++) {
            float ex = expf(l[j] - mx);
            l[j] = ex;
            s += ex;
        }
        float iv = 1.0f / s;
        #pragma unroll
        for (int j = 0; j < KK; j++) lgs0[j][h] = l[j] * iv;
    }
    __syncthreads();

    // ---- P4: attention-weighted sums ----
    if (tid < 64) {
        int e = tid, h = e >> 4;
        float acc = 0.0f;
        #pragma unroll
        for (int j = 0; j < KK; j++) acc += lgs0[j][h] * v0s[j][e];
        o0s[e] = acc;
    } else if (tid < 112) {
        int idx = tid - 64, e = idx / 3, m = idx % 3, h = e >> 2;
        float acc = 0.0f;
        #pragma unroll
        for (int j = 0; j < KK; j++) acc += lgs0[j][h] * v1s[j][e * 3 + m];
        o1s[idx] = acc;
    }
    __syncthreads();

    // ---- P5: output projection + residual ----
    if (tid < 64) {
        int c = tid;
        float acc = 0.0f;
        #pragma unroll
        for (int e = 0; e < D0; e++) acc += o0s[e] * Wo0[e * D0 + c];
        f0b[(size_t)node * D0 + c] += acc;
    } else if (tid < 112) {
        int idx = tid - 64, f = idx / 3, m = idx % 3;
        float acc = 0.0f;
        #pragma unroll
        for (int c = 0; c < D1; c++) acc += o1s[c * 3 + m] * Wo1[c * D1 + f];
        f1b[(size_t)node * D13 + idx] += acc;
    }
}

// ---------------- fused FFN (prenorm + MLPs + gate) ----------------
__global__ __launch_bounds__(256) void ffn_kernel(
    const float* __restrict__ F0w1, const float* __restrict__ F0w2,
    const float* __restrict__ F1w1, const float* __restrict__ F1w2,
    float* __restrict__ f0b, float* __restrict__ f1b) {

    int node = blockIdx.x;
    int tid  = threadIdx.x;
    __shared__ float g0s[D0], g1s[D13], ts[256], us[D13 * 4];  // us: 64 x 3

    if (tid < 64) {
        float x  = f0b[(size_t)node * D0 + tid];
        float mu = wred(x) * (1.0f / D0);
        float dv = x - mu;
        float var = wred(dv * dv) * (1.0f / D0);
        g0s[tid] = dv * rsqrtf(var + EPS);
    } else if (tid < 128) {
        int lane = tid - 64;
        float w = (lane < D13) ? f1b[(size_t)node * D13 + lane] : 0.0f;
        float t = wred(w * w);
        float rms = rsqrtf(t * (1.0f / D1) + EPS);
        if (lane < D13) g1s[lane] = w * rms;
    }
    __syncthreads();

    {   // hidden layer of scalar FFN (d0 -> 4*d0 = 256)
        float acc = 0.0f;
        #pragma unroll
        for (int c = 0; c < D0; c++) acc += g0s[c] * F0w1[c * 256 + tid];
        ts[tid] = gelu_t(acc);
    }
    if (tid < 192) {  // u1 = g1 @ F1w1 : (d1,3) -> (64,3)
        int e = tid / 3, m = tid % 3;
        float acc = 0.0f;
        #pragma unroll
        for (int c = 0; c < D1; c++) acc += g1s[c * 3 + m] * F1w1[c * 64 + e];
        us[tid] = acc;
    }
    __syncthreads();

    if (tid < 64) {  // gate
        int e = tid;
        float a = us[e * 3], b = us[e * 3 + 1], c = us[e * 3 + 2];
        float nrm = sqrtf(a * a + b * b + c * c);
        float gate = 1.0f / (1.0f + expf(-nrm));
        us[e * 3 + 0] *= gate;
        us[e * 3 + 1] *= gate;
        us[e * 3 + 2] *= gate;
    }
    __syncthreads();

    if (tid < 64) {
        int c = tid;
        float acc = 0.0f;
        #pragma unroll
        for (int j = 0; j < 256; j++) acc += ts[j] * F0w2[j * D0 + c];
        f0b[(size_t)node * D0 + c] += acc;
    } else if (tid < 112) {
        int idx = tid - 64, f = idx / 3, m = idx % 3;
        float acc = 0.0f;
        #pragma unroll
        for (int e = 0; e < 64; e++) acc += us[e * 3 + m] * F1w2[e * D1 + f];
        f1b[(size_t)node * D13 + idx] += acc;
    }
}

// ---------------- final concat ----------------
__global__ void concat_kernel(const float* __restrict__ f0b,
                              const float* __restrict__ f1b,
                              float* __restrict__ out) {
    int i = blockIdx.x * blockDim.x + threadIdx.x;
    if (i >= BB * NN * (D0 + D13)) return;
    int node = i / (D0 + D13), c = i % (D0 + D13);
    out[i] = (c < D0) ? f0b[(size_t)node * D0 + c]
                      : f1b[(size_t)node * D13 + (c - D0)];
}

extern "C" void kernel_launch(void* const* d_in, const int* in_sizes, int n_in,
                              void* d_out, int out_size, void* d_ws, size_t ws_size,
                              hipStream_t stream) {
    const float* f0     = (const float*)d_in[0];
    const float* f1     = (const float*)d_in[1];
    const float* coords = (const float*)d_in[2];
    const int*   nbr    = (const int*)d_in[3];
    const float* Wq0    = (const float*)d_in[4];
    const float* Wq1    = (const float*)d_in[5];
    const float* Wk00   = (const float*)d_in[6];
    const float* Wk10   = (const float*)d_in[7];
    const float* Wk01   = (const float*)d_in[8];
    const float* Wk11   = (const float*)d_in[9];
    const float* Wk11r  = (const float*)d_in[10];
    const float* Wv00   = (const float*)d_in[11];
    const float* Wv10   = (const float*)d_in[12];
    const float* Wv01   = (const float*)d_in[13];
    const float* Wv11   = (const float*)d_in[14];
    const float* Wv11r  = (const float*)d_in[15];
    const float* Rw1    = (const float*)d_in[16];
    const float* Rb1    = (const float*)d_in[17];
    const float* Rw20   = (const float*)d_in[18];
    const float* Rw21   = (const float*)d_in[19];
    const float* Wo0    = (const float*)d_in[20];
    const float* Wo1    = (const float*)d_in[21];
    const float* F0w1   = (const float*)d_in[22];
    const float* F0w2   = (const float*)d_in[23];
    const float* F1w1   = (const float*)d_in[24];
    const float* F1w2   = (const float*)d_in[25];
    float* out = (float*)d_out;

    // workspace layout
    float* ws    = (float*)d_ws;
    float* f0b   = ws;                 ws += (size_t)BB * NN * D0;
    float* f1b   = ws;                 ws += (size_t)BB * NN * D13;
    float* g0b   = ws;                 ws += (size_t)BB * NN * D0;
    float* g1b   = ws;                 ws += (size_t)BB * NN * D13;
    float* rhatb = ws;                 ws += (size_t)BB * NN * KK * 3;
    float* distb = ws;                 ws += (size_t)BB * NN * KK;

    int nodes = BB * NN;
    int edges = BB * NN * KK;

    geom_kernel<<<(edges + 255) / 256, 256, 0, stream>>>(coords, nbr, rhatb, distb);
    hipMemcpyAsync(f0b, f0, (size_t)nodes * D0 * sizeof(float),
                   hipMemcpyDeviceToDevice, stream);
    hipMemcpyAsync(f1b, f1, (size_t)nodes * D13 * sizeof(float),
                   hipMemcpyDeviceToDevice, stream);

    for (int l = 0; l < NLAYER; l++) {
        prenorm_kernel<<<nodes, 64, 0, stream>>>(f0b, f1b, g0b, g1b);
        attn_kernel<<<nodes, 256, 0, stream>>>(
            g0b, g1b, nbr, rhatb, distb,
            Wq0 + l * D0 * D0, Wq1 + l * D1 * D1,
            Wk00 + l * D0 * D0, Wk10 + l * D1 * D0,
            Wk01 + l * D0 * D1, Wk11 + l * D1 * D1, Wk11r + l * D1 * D1,
            Wv00 + l * D0 * D0, Wv10 + l * D1 * D0,
            Wv01 + l * D0 * D1, Wv11 + l * D1 * D1, Wv11r + l * D1 * D1,
            Rw1 + l * RHD, Rb1 + l * RHD,
            Rw20 + l * RHD * D0, Rw21 + l * RHD * D1,
            Wo0 + l * D0 * D0, Wo1 + l * D1 * D1,
            f0b, f1b);
        ffn_kernel<<<nodes, 256, 0, stream>>>(
            F0w1 + l * D0 * 256, F0w2 + l * 256 * D0,
            F1w1 + l * D1 * 64, F1w2 + l * 64 * D1,
            f0b, f1b);
    }

    concat_kernel<<<(nodes * (D0 + D13) + 255) / 256, 256, 0, stream>>>(f0b, f1b, out);
}

// Round 5
// 545.647 us; speedup vs baseline: 11.3690x; 2.9818x over previous
//
#include <hip/hip_runtime.h>
#include <math.h>

// Problem constants (b=2, n=4096, k=32, d0=64, d1=16, L=2, rh=16, HEADS=4)
#define BB    2
#define NN    4096
#define KK    32
#define D0    64
#define D1    16
#define D13   48
#define RHD   16
#define NHEAD 4
#define NLAYER 2
#define EPS   1e-6f
#define SCALE 0.18898223650461363f   // 1/sqrt(16 + 12)
#define ETOT  (BB*NN*KK)             // 262144 edges
#define AST   136                    // LDS A stride (bf16 elems), 272B row: 2-way bank alias only
#define ARST  40                     // LDS Ar stride (80B row, 16B-aligned)

typedef float  f32x4 __attribute__((ext_vector_type(4)));
typedef short  s16x8 __attribute__((ext_vector_type(8)));
#define MFMA16(a,b,c) __builtin_amdgcn_mfma_f32_16x16x32_bf16(a,b,c,0,0,0)

__device__ __forceinline__ unsigned short f2bf(float x) {
    union { float f; unsigned u; } v; v.f = x;
    unsigned r = v.u + 0x7fffu + ((v.u >> 16) & 1u);
    return (unsigned short)(r >> 16);
}
__device__ __forceinline__ float bf2f(unsigned short h) {
    union { unsigned u; float f; } v; v.u = ((unsigned)h) << 16;
    return v.f;
}
// exact-ish hi/lo split: hi + lo represents x to ~2^-17 rel
__device__ __forceinline__ void split_bf(float x, unsigned short* hi, unsigned short* lo) {
    unsigned short h = f2bf(x);
    *hi = h;
    *lo = f2bf(x - bf2f(h));
}

// 3-product split-precision MFMA: (ah+al)@(bh+bl) minus al@bl term
__device__ __forceinline__ f32x4 mm3(s16x8 ah, s16x8 al, s16x8 bh, s16x8 bl, f32x4 c) {
    c = MFMA16(ah, bh, c);
    c = MFMA16(ah, bl, c);
    c = MFMA16(al, bh, c);
    return c;
}

__device__ __forceinline__ float wred(float v) {
    #pragma unroll
    for (int o = 32; o > 0; o >>= 1) v += __shfl_xor(v, o, 64);
    return v;
}

__device__ __forceinline__ float gelu_t(float x) {
    float x3 = x * x * x;
    return 0.5f * x * (1.0f + tanhf(0.7978845608028654f * (x + 0.044715f * x3)));
}

// ---------------- geometry ----------------
__global__ void geom_kernel(const float* __restrict__ coords,
                            const int* __restrict__ nbr,
                            float* __restrict__ rhat,
                            float* __restrict__ dist) {
    int e = blockIdx.x * blockDim.x + threadIdx.x;
    if (e >= ETOT) return;
    int bn = e / KK;
    int bb = bn / NN;
    int j  = nbr[e];
    const float* cs = coords + (size_t)bn * 3;
    const float* cn = coords + ((size_t)bb * NN + j) * 3;
    float rx = cn[0] - cs[0], ry = cn[1] - cs[1], rz = cn[2] - cs[2];
    float d  = sqrtf(rx * rx + ry * ry + rz * rz);
    float iv = 1.0f / (d + EPS);
    rhat[e * 3 + 0] = rx * iv;
    rhat[e * 3 + 1] = ry * iv;
    rhat[e * 3 + 2] = rz * iv;
    dist[e] = d;
}

// ---------------- prenorm + q projections ----------------
__global__ __launch_bounds__(64) void prenorm_q_kernel(
    const float* __restrict__ f0, const float* __restrict__ f1,
    const float* __restrict__ Wq0, const float* __restrict__ Wq1,
    float* __restrict__ g0, float* __restrict__ g1,
    float* __restrict__ q0, float* __restrict__ q1) {
    int node = blockIdx.x;
    int lane = threadIdx.x;
    __shared__ float g0s[D0], g1s[D13];

    float x  = f0[(size_t)node * D0 + lane];
    float mu = wred(x) * (1.0f / D0);
    float dv = x - mu;
    float var = wred(dv * dv) * (1.0f / D0);
    float g0v = dv * rsqrtf(var + EPS);
    g0[(size_t)node * D0 + lane] = g0v;
    g0s[lane] = g0v;

    float w = (lane < D13) ? f1[(size_t)node * D13 + lane] : 0.0f;
    float t = wred(w * w);
    float rms = rsqrtf(t * (1.0f / D1) + EPS);
    if (lane < D13) {
        float g1v = w * rms;
        g1[(size_t)node * D13 + lane] = g1v;
        g1s[lane] = g1v;
    }
    __syncthreads();

    float acc = 0.0f;
    #pragma unroll
    for (int c = 0; c < D0; c++) acc += g0s[c] * Wq0[c * D0 + lane];
    q0[(size_t)node * D0 + lane] = acc;
    if (lane < D13) {
        int e = lane / 3, m = lane % 3;
        float a1 = 0.0f;
        #pragma unroll
        for (int c = 0; c < D1; c++) a1 += g1s[c * 3 + m] * Wq1[c * D1 + e];
        q1[(size_t)node * D13 + lane] = a1;
    }
}

// ---------------- weight pack values ----------------
// GEMM1 B (n in [0,128): [k0|v0], k in [0,96)): rows 0:64 h0, 64:80 dot1, 80:96 zero
__device__ __forceinline__ float B1val(int n, int k,
    const float* Wk00, const float* Wk10, const float* Wv00, const float* Wv10) {
    int nn = n & 63;
    const float* W0 = (n < 64) ? Wk00 : Wv00;
    const float* W1 = (n < 64) ? Wk10 : Wv10;
    if (k < 64) return W0[k * D0 + nn];
    if (k < 80) return W1[(k - 64) * D0 + nn];
    return 0.0f;
}
// GEMM2 B (n in [0,128): [sk|sv|hk(m=0..2)|hv(m=0..2)], k in [0,128)):
// k rows: 0:64 h0, 64:80 dot1, 80:128 h1 (m-major: k=80+m*16+c)
__device__ __forceinline__ float B2val(int n, int k,
    const float* Wk01, const float* Wk11, const float* Wk11r,
    const float* Wv01, const float* Wv11, const float* Wv11r) {
    if (n < 16) {
        if (k < 64) return Wk01[k * D1 + n];
        if (k < 80) return Wk11r[(k - 64) * D1 + n];
        return 0.0f;
    }
    if (n < 32) {
        int e = n - 16;
        if (k < 64) return Wv01[k * D1 + e];
        if (k < 80) return Wv11r[(k - 64) * D1 + e];
        return 0.0f;
    }
    if (n < 80) {
        int m = (n - 32) >> 4, e = (n - 32) & 15;
        if (k >= 80) { int mm = (k - 80) >> 4, c = (k - 80) & 15; if (mm == m) return Wk11[c * D1 + e]; }
        return 0.0f;
    }
    { int m = (n - 80) >> 4, e = (n - 80) & 15;
      if (k >= 80) { int mm = (k - 80) >> 4, c = (k - 80) & 15; if (mm == m) return Wv11[c * D1 + e]; }
      return 0.0f; }
}

// pack layout: P[((ks*NT + nt)*64 + lane)*8 + t] = val(n = nt*16 + (lane&15), k = ks*32 + (lane>>4)*8 + t)
__global__ void prep_kernel(
    const float* __restrict__ Wk00, const float* __restrict__ Wk10,
    const float* __restrict__ Wk01, const float* __restrict__ Wk11,
    const float* __restrict__ Wk11r,
    const float* __restrict__ Wv00, const float* __restrict__ Wv10,
    const float* __restrict__ Wv01, const float* __restrict__ Wv11,
    const float* __restrict__ Wv11r,
    const float* __restrict__ Rw20, const float* __restrict__ Rw21,
    unsigned short* __restrict__ B1H, unsigned short* __restrict__ B1L,
    unsigned short* __restrict__ B2H, unsigned short* __restrict__ B2L,
    unsigned short* __restrict__ R0H, unsigned short* __restrict__ R0L,
    unsigned short* __restrict__ R1H, unsigned short* __restrict__ R1L) {
    int id = blockIdx.x * 256 + threadIdx.x;
    if (id < 1536) {                       // B1: KS=3, NT=8
        int ks = id >> 9, rem = id & 511, nt = rem >> 6, lane = rem & 63;
        int li = lane & 15, quad = lane >> 4;
        #pragma unroll
        for (int t = 0; t < 8; t++) {
            float v = B1val(nt * 16 + li, ks * 32 + quad * 8 + t, Wk00, Wk10, Wv00, Wv10);
            split_bf(v, &B1H[id * 8 + t], &B1L[id * 8 + t]);
        }
    } else if (id < 3584) {                // B2: KS=4, NT=8
        int id2 = id - 1536;
        int ks = id2 >> 9, rem = id2 & 511, nt = rem >> 6, lane = rem & 63;
        int li = lane & 15, quad = lane >> 4;
        #pragma unroll
        for (int t = 0; t < 8; t++) {
            float v = B2val(nt * 16 + li, ks * 32 + quad * 8 + t,
                            Wk01, Wk11, Wk11r, Wv01, Wv11, Wv11r);
            split_bf(v, &B2H[id2 * 8 + t], &B2L[id2 * 8 + t]);
        }
    } else if (id < 3840) {                // R0: KS=1, NT=4 (K=32 padded, real K=16)
        int id2 = id - 3584;
        int nt = id2 >> 6, lane = id2 & 63;
        int li = lane & 15, quad = lane >> 4;
        #pragma unroll
        for (int t = 0; t < 8; t++) {
            int k = quad * 8 + t;
            float v = (k < 16) ? Rw20[k * D0 + nt * 16 + li] : 0.0f;
            split_bf(v, &R0H[id2 * 8 + t], &R0L[id2 * 8 + t]);
        }
    } else if (id < 3904) {                // R1: KS=1, NT=1
        int id2 = id - 3840;
        int li = id2 & 15, quad = id2 >> 4;
        #pragma unroll
        for (int t = 0; t < 8; t++) {
            int k = quad * 8 + t;
            float v = (k < 16) ? Rw21[k * D1 + li] : 0.0f;
            split_bf(v, &R1H[id2 * 8 + t], &R1L[id2 * 8 + t]);
        }
    }
}

// ---------------- fused attention: 64 edges (2 nodes) per 128-thread block ----
// wave w owns node w (rows w*32..w*32+31). Split-precision MFMA GEMMs; softmax,
// weighted sums, and output projection are wave-local. LDS = 60KB static.
// NOTE: no occupancy floor (R2: __launch_bounds__(...,4) caused VGPR=64 + GB-scale spills)
__global__ __launch_bounds__(128) void attn_fused_kernel(
    const float* __restrict__ g0g, const float* __restrict__ g1g,
    const int* __restrict__ nbr_idx,
    const float* __restrict__ rhatg, const float* __restrict__ distg,
    const float* __restrict__ q0g, const float* __restrict__ q1g,
    const float* __restrict__ Rw1, const float* __restrict__ Rb1,
    const unsigned short* __restrict__ B1H, const unsigned short* __restrict__ B1L,
    const unsigned short* __restrict__ B2H, const unsigned short* __restrict__ B2L,
    const unsigned short* __restrict__ R0H, const unsigned short* __restrict__ R0L,
    const unsigned short* __restrict__ R1H, const unsigned short* __restrict__ R1L,
    const float* __restrict__ Wo0, const float* __restrict__ Wo1,
    float* __restrict__ f0b, float* __restrict__ f1b) {

    int B0    = blockIdx.x * 64;       // first edge
    int node0 = blockIdx.x * 2;        // first node
    int bb    = node0 >> 12;           // / NN
    int tid   = threadIdx.x;
    int lane  = tid & 63, w = tid >> 6;      // w = wave = node-local
    int li    = lane & 15, quad = lane >> 4;

    __shared__ unsigned short AsH[64][AST], AsL[64][AST];   // 34,816 B
    __shared__ unsigned short ArH[64][ARST], ArL[64][ARST]; // 10,240 B
    __shared__ float rhts[64 * 3];   // 768
    __shared__ float dsts[64];       // 256
    __shared__ float q0s[2 * D0];    // 512
    __shared__ float q1s[2 * D13];   // 384
    __shared__ int   idxs[64];       // 256
    __shared__ float lgs[64][4];     // 1024 (logits, then softmax weights)
    __shared__ float v1s[64][48];    // 12,288
    __shared__ float o0s[2][D0];     // 512
    __shared__ float o1s[2][D13];    // 384

    // ---- stage meta ----
    if (tid < 64) {
        idxs[tid] = nbr_idx[B0 + tid];
        dsts[tid] = distg[B0 + tid];
        rhts[tid]       = rhatg[(size_t)B0 * 3 + tid];
        rhts[tid + 64]  = rhatg[(size_t)B0 * 3 + tid + 64];
        rhts[tid + 128] = rhatg[(size_t)B0 * 3 + tid + 128];
    }
    q0s[tid] = q0g[(size_t)node0 * D0 + tid];
    if (tid < 96) q1s[tid] = q1g[(size_t)node0 * D13 + tid];
    __syncthreads();

    // ---- build A (hi/lo): cols 0:64 h0, 64:80 dot1, 80:128 h1 (m-major) ----
    #pragma unroll
    for (int it = 0; it < 4; it++) {               // 512 tasks (j, c8)
        int v = tid + it * 128;
        int j = v >> 3, c8 = (v & 7) * 8;
        const float* src = g0g + ((size_t)bb * NN + idxs[j]) * D0 + c8;
        float4 x = *(const float4*)src;
        float4 y = *(const float4*)(src + 4);
        split_bf(x.x, &AsH[j][c8 + 0], &AsL[j][c8 + 0]);
        split_bf(x.y, &AsH[j][c8 + 1], &AsL[j][c8 + 1]);
        split_bf(x.z, &AsH[j][c8 + 2], &AsL[j][c8 + 2]);
        split_bf(x.w, &AsH[j][c8 + 3], &AsL[j][c8 + 3]);
        split_bf(y.x, &AsH[j][c8 + 4], &AsL[j][c8 + 4]);
        split_bf(y.y, &AsH[j][c8 + 5], &AsL[j][c8 + 5]);
        split_bf(y.z, &AsH[j][c8 + 6], &AsL[j][c8 + 6]);
        split_bf(y.w, &AsH[j][c8 + 7], &AsL[j][c8 + 7]);
    }
    #pragma unroll
    for (int it = 0; it < 8; it++) {               // 1024 tasks (j, c)
        int v = tid + it * 128;
        int j = v >> 4, c = v & 15;
        const float* src = g1g + ((size_t)bb * NN + idxs[j]) * D13 + c * 3;
        float a = src[0], b = src[1], cc = src[2];
        float d = a * rhts[j * 3] + b * rhts[j * 3 + 1] + cc * rhts[j * 3 + 2];
        split_bf(d,  &AsH[j][64 + c],  &AsL[j][64 + c]);
        split_bf(a,  &AsH[j][80 + c],  &AsL[j][80 + c]);
        split_bf(b,  &AsH[j][96 + c],  &AsL[j][96 + c]);
        split_bf(cc, &AsH[j][112 + c], &AsL[j][112 + c]);
    }
    #pragma unroll
    for (int it = 0; it < 8; it++) {               // 1024 tasks (j, u): radial hidden
        int v = tid + it * 128;
        int j = v >> 4, u = v & 15;
        float x = gelu_t(dsts[j] * Rw1[u] + Rb1[u]);
        split_bf(x, &ArH[j][u], &ArL[j][u]);
        ArH[j][16 + u] = 0; ArL[j][16 + u] = 0;    // K-pad
    }
    __syncthreads();

    int mrow0 = w * 32 + li;
    int koff  = quad * 8;

    // ---- GEMM_r: r0[j][c] / r1[j][e] via MFMA (C-layout matches main accs) ----
    f32x4 r0a[2][4], r1a[2];
    #pragma unroll
    for (int i = 0; i < 2; i++) {
        #pragma unroll
        for (int j = 0; j < 4; j++) r0a[i][j] = (f32x4){0.f, 0.f, 0.f, 0.f};
        r1a[i] = (f32x4){0.f, 0.f, 0.f, 0.f};
    }
    {
        s16x8 rah0 = *(const s16x8*)&ArH[mrow0][koff];
        s16x8 ral0 = *(const s16x8*)&ArL[mrow0][koff];
        s16x8 rah1 = *(const s16x8*)&ArH[mrow0 + 16][koff];
        s16x8 ral1 = *(const s16x8*)&ArL[mrow0 + 16][koff];
        #pragma unroll
        for (int nt = 0; nt < 4; nt++) {
            s16x8 bh = *(const s16x8*)(R0H + (nt * 64 + lane) * 8);
            s16x8 bl = *(const s16x8*)(R0L + (nt * 64 + lane) * 8);
            r0a[0][nt] = mm3(rah0, ral0, bh, bl, r0a[0][nt]);
            r0a[1][nt] = mm3(rah1, ral1, bh, bl, r0a[1][nt]);
        }
        s16x8 bh = *(const s16x8*)(R1H + lane * 8);
        s16x8 bl = *(const s16x8*)(R1L + lane * 8);
        r1a[0] = mm3(rah0, ral0, bh, bl, r1a[0]);
        r1a[1] = mm3(rah1, ral1, bh, bl, r1a[1]);
    }

    // ---- GEMM2: A[64x128] @ B2[128x128] -> sk|sv|hk|hv ----
    f32x4 acc[2][8];
    #pragma unroll
    for (int i = 0; i < 2; i++)
        #pragma unroll
        for (int j = 0; j < 8; j++) acc[i][j] = (f32x4){0.f, 0.f, 0.f, 0.f};
    #pragma unroll
    for (int ks = 0; ks < 4; ks++) {
        int k0 = ks * 32 + koff;
        s16x8 ah0 = *(const s16x8*)&AsH[mrow0][k0];
        s16x8 al0 = *(const s16x8*)&AsL[mrow0][k0];
        s16x8 ah1 = *(const s16x8*)&AsH[mrow0 + 16][k0];
        s16x8 al1 = *(const s16x8*)&AsL[mrow0 + 16][k0];
        #pragma unroll
        for (int nt = 0; nt < 8; nt++) {
            s16x8 bh = *(const s16x8*)(B2H + ((ks * 8 + nt) * 64 + lane) * 8);
            s16x8 bl = *(const s16x8*)(B2L + ((ks * 8 + nt) * 64 + lane) * 8);
            acc[0][nt] = mm3(ah0, al0, bh, bl, acc[0][nt]);
            acc[1][nt] = mm3(ah1, al1, bh, bl, acc[1][nt]);
        }
    }

    // ---- epilogue2: k1/v1 assembly; q1.k1 -> lgs (initial write); v1 -> LDS ----
    #pragma unroll
    for (int mt = 0; mt < 2; mt++) {
        #pragma unroll
        for (int r = 0; r < 4; r++) {
            int j = w * 32 + mt * 16 + quad * 4 + r;
            float r1  = r1a[mt][r];
            float rh0 = rhts[j * 3], rh1 = rhts[j * 3 + 1], rh2 = rhts[j * 3 + 2];
            float sk = acc[mt][0][r], sv = acc[mt][1][r];
            float k1a = (sk * rh0 + acc[mt][2][r]) * r1;
            float k1b = (sk * rh1 + acc[mt][3][r]) * r1;
            float k1c = (sk * rh2 + acc[mt][4][r]) * r1;
            v1s[j][li * 3 + 0] = (sv * rh0 + acc[mt][5][r]) * r1;
            v1s[j][li * 3 + 1] = (sv * rh1 + acc[mt][6][r]) * r1;
            v1s[j][li * 3 + 2] = (sv * rh2 + acc[mt][7][r]) * r1;
            int qb = w * D13 + li * 3;
            float lc = q1s[qb] * k1a + q1s[qb + 1] * k1b + q1s[qb + 2] * k1c;
            lc += __shfl_xor(lc, 1, 4);
            lc += __shfl_xor(lc, 2, 4);
            if ((li & 3) == 0) lgs[j][li >> 2] = lc;
        }
    }
    __syncthreads();

    // ---- GEMM1: A[64x96] @ B1[96x128] -> k0|v0 ----
    #pragma unroll
    for (int i = 0; i < 2; i++)
        #pragma unroll
        for (int j = 0; j < 8; j++) acc[i][j] = (f32x4){0.f, 0.f, 0.f, 0.f};
    #pragma unroll
    for (int ks = 0; ks < 3; ks++) {
        int k0 = ks * 32 + koff;
        s16x8 ah0 = *(const s16x8*)&AsH[mrow0][k0];
        s16x8 al0 = *(const s16x8*)&AsL[mrow0][k0];
        s16x8 ah1 = *(const s16x8*)&AsH[mrow0 + 16][k0];
        s16x8 al1 = *(const s16x8*)&AsL[mrow0 + 16][k0];
        #pragma unroll
        for (int nt = 0; nt < 8; nt++) {
            s16x8 bh = *(const s16x8*)(B1H + ((ks * 8 + nt) * 64 + lane) * 8);
            s16x8 bl = *(const s16x8*)(B1L + ((ks * 8 + nt) * 64 + lane) * 8);
            acc[0][nt] = mm3(ah0, al0, bh, bl, acc[0][nt]);
            acc[1][nt] = mm3(ah1, al1, bh, bl, acc[1][nt]);
        }
    }

    // ---- epilogue1: q0.k0 logits added into lgs (v0 stays in acc registers) ----
    #pragma unroll
    for (int mt = 0; mt < 2; mt++) {
        int jb = w * 32 + mt * 16 + quad * 4;
        #pragma unroll
        for (int nt = 0; nt < 4; nt++) {
            float q0e = q0s[w * D0 + nt * 16 + li];
            float p[4];
            #pragma unroll
            for (int r = 0; r < 4; r++)
                p[r] = q0e * (acc[mt][nt][r] * r0a[mt][nt][r]);
            #pragma unroll
            for (int off = 1; off < 16; off <<= 1) {
                #pragma unroll
                for (int r = 0; r < 4; r++) p[r] += __shfl_xor(p[r], off, 16);
            }
            if (li == 0) {
                #pragma unroll
                for (int r = 0; r < 4; r++) lgs[jb + r][nt] += p[r];
            }
        }
    }
    __syncthreads();

    // ---- softmax (per node = per wave; lanes 0..3 = heads) ----
    if (lane < NHEAD) {
        int h = lane;
        float mx = -1e30f;
        for (int jn = 0; jn < KK; jn++) mx = fmaxf(mx, lgs[w * 32 + jn][h]);
        float mxs = mx * SCALE;
        float s = 0.0f;
        for (int jn = 0; jn < KK; jn++) {
            float ex = expf(lgs[w * 32 + jn][h] * SCALE - mxs);
            lgs[w * 32 + jn][h] = ex;
            s += ex;
        }
        float iv = 1.0f / s;
        for (int jn = 0; jn < KK; jn++) lgs[w * 32 + jn][h] *= iv;
    }
    __syncthreads();

    // ---- weighted sums: o0 from acc registers (cross-quad reduce), o1 from LDS ----
    #pragma unroll
    for (int nt = 0; nt < 4; nt++) {
        float p = 0.0f;
        #pragma unroll
        for (int mt = 0; mt < 2; mt++)
            #pragma unroll
            for (int r = 0; r < 4; r++) {
                int j = w * 32 + mt * 16 + quad * 4 + r;
                p += lgs[j][nt] * (acc[mt][nt + 4][r] * r0a[mt][nt][r]);
            }
        p += __shfl_xor(p, 16, 64);
        p += __shfl_xor(p, 32, 64);
        if (quad == 0) o0s[w][nt * 16 + li] = p;
    }
    if (lane < D13) {
        int h = (lane / 3) >> 2;
        float p = 0.0f;
        #pragma unroll
        for (int jn = 0; jn < KK; jn++)
            p += lgs[w * 32 + jn][h] * v1s[w * 32 + jn][lane];
        o1s[w][lane] = p;
    }
    __syncthreads();

    // ---- output projections + residual (per wave/node) ----
    {
        float a0 = 0.0f;
        #pragma unroll
        for (int e = 0; e < D0; e++) a0 += o0s[w][e] * Wo0[e * D0 + lane];
        f0b[(size_t)(node0 + w) * D0 + lane] += a0;
    }
    if (lane < D13) {
        int f = lane / 3, m = lane % 3;
        float a1 = 0.0f;
        #pragma unroll
        for (int c = 0; c < D1; c++) a1 += o1s[w][c * 3 + m] * Wo1[c * D1 + f];
        f1b[(size_t)(node0 + w) * D13 + lane] += a1;
    }
}

// ---------------- fused FFN ----------------
__global__ __launch_bounds__(256) void ffn_kernel(
    const float* __restrict__ F0w1, const float* __restrict__ F0w2,
    const float* __restrict__ F1w1, const float* __restrict__ F1w2,
    float* __restrict__ f0b, float* __restrict__ f1b) {
    int node = blockIdx.x;
    int tid  = threadIdx.x;
    __shared__ float g0s[D0], g1s[D13], ts[256], us[D13 * 4];

    if (tid < 64) {
        float x  = f0b[(size_t)node * D0 + tid];
        float mu = wred(x) * (1.0f / D0);
        float dv = x - mu;
        float var = wred(dv * dv) * (1.0f / D0);
        g0s[tid] = dv * rsqrtf(var + EPS);
    } else if (tid < 128) {
        int lane = tid - 64;
        float ww = (lane < D13) ? f1b[(size_t)node * D13 + lane] : 0.0f;
        float t = wred(ww * ww);
        float rms = rsqrtf(t * (1.0f / D1) + EPS);
        if (lane < D13) g1s[lane] = ww * rms;
    }
    __syncthreads();

    {
        float acc = 0.0f;
        #pragma unroll
        for (int c = 0; c < D0; c++) acc += g0s[c] * F0w1[c * 256 + tid];
        ts[tid] = gelu_t(acc);
    }
    if (tid < 192) {
        int e = tid / 3, m = tid % 3;
        float acc = 0.0f;
        #pragma unroll
        for (int c = 0; c < D1; c++) acc += g1s[c * 3 + m] * F1w1[c * 64 + e];
        us[tid] = acc;
    }
    __syncthreads();

    if (tid < 64) {
        int e = tid;
        float a = us[e * 3], b = us[e * 3 + 1], c = us[e * 3 + 2];
        float nrm = sqrtf(a * a + b * b + c * c);
        float gate = 1.0f / (1.0f + expf(-nrm));
        us[e * 3 + 0] *= gate;
        us[e * 3 + 1] *= gate;
        us[e * 3 + 2] *= gate;
    }
    __syncthreads();

    if (tid < 64) {
        float acc = 0.0f;
        #pragma unroll
        for (int j = 0; j < 256; j++) acc += ts[j] * F0w2[j * D0 + tid];
        f0b[(size_t)node * D0 + tid] += acc;
    } else if (tid < 112) {
        int idx = tid - 64, f = idx / 3, m = idx % 3;
        float acc = 0.0f;
        #pragma unroll
        for (int e = 0; e < 64; e++) acc += us[e * 3 + m] * F1w2[e * D1 + f];
        f1b[(size_t)node * D13 + idx] += acc;
    }
}

// ---------------- final concat ----------------
__global__ void concat_kernel(const float* __restrict__ f0b,
                              const float* __restrict__ f1b,
                              float* __restrict__ out) {
    int i = blockIdx.x * blockDim.x + threadIdx.x;
    if (i >= BB * NN * (D0 + D13)) return;
    int node = i / (D0 + D13), c = i % (D0 + D13);
    out[i] = (c < D0) ? f0b[(size_t)node * D0 + c]
                      : f1b[(size_t)node * D13 + (c - D0)];
}

extern "C" void kernel_launch(void* const* d_in, const int* in_sizes, int n_in,
                              void* d_out, int out_size, void* d_ws, size_t ws_size,
                              hipStream_t stream) {
    const float* f0     = (const float*)d_in[0];
    const float* f1     = (const float*)d_in[1];
    const float* coords = (const float*)d_in[2];
    const int*   nbr    = (const int*)d_in[3];
    const float* Wq0    = (const float*)d_in[4];
    const float* Wq1    = (const float*)d_in[5];
    const float* Wk00   = (const float*)d_in[6];
    const float* Wk10   = (const float*)d_in[7];
    const float* Wk01   = (const float*)d_in[8];
    const float* Wk11   = (const float*)d_in[9];
    const float* Wk11r  = (const float*)d_in[10];
    const float* Wv00   = (const float*)d_in[11];
    const float* Wv10   = (const float*)d_in[12];
    const float* Wv01   = (const float*)d_in[13];
    const float* Wv11   = (const float*)d_in[14];
    const float* Wv11r  = (const float*)d_in[15];
    const float* Rw1    = (const float*)d_in[16];
    const float* Rb1    = (const float*)d_in[17];
    const float* Rw20   = (const float*)d_in[18];
    const float* Rw21   = (const float*)d_in[19];
    const float* Wo0    = (const float*)d_in[20];
    const float* Wo1    = (const float*)d_in[21];
    const float* F0w1   = (const float*)d_in[22];
    const float* F0w2   = (const float*)d_in[23];
    const float* F1w1   = (const float*)d_in[24];
    const float* F1w2   = (const float*)d_in[25];
    float* out = (float*)d_out;

    int nodes = BB * NN;

    // workspace layout (~22 MB total)
    float* wf = (float*)d_ws;
    float* f0b   = wf; wf += (size_t)nodes * D0;
    float* f1b   = wf; wf += (size_t)nodes * D13;
    float* g0b   = wf; wf += (size_t)nodes * D0;
    float* g1b   = wf; wf += (size_t)nodes * D13;
    float* q0b   = wf; wf += (size_t)nodes * D0;
    float* q1b   = wf; wf += (size_t)nodes * D13;
    float* rhatb = wf; wf += (size_t)ETOT * 3;
    float* distb = wf; wf += (size_t)ETOT;
    unsigned short* wu = (unsigned short*)wf;
    unsigned short* B1H = wu; wu += 1536 * 8;
    unsigned short* B1L = wu; wu += 1536 * 8;
    unsigned short* B2H = wu; wu += 2048 * 8;
    unsigned short* B2L = wu; wu += 2048 * 8;
    unsigned short* R0H = wu; wu += 256 * 8;
    unsigned short* R0L = wu; wu += 256 * 8;
    unsigned short* R1H = wu; wu += 64 * 8;
    unsigned short* R1L = wu; wu += 64 * 8;

    geom_kernel<<<(ETOT + 255) / 256, 256, 0, stream>>>(coords, nbr, rhatb, distb);
    hipMemcpyAsync(f0b, f0, (size_t)nodes * D0 * sizeof(float),
                   hipMemcpyDeviceToDevice, stream);
    hipMemcpyAsync(f1b, f1, (size_t)nodes * D13 * sizeof(float),
                   hipMemcpyDeviceToDevice, stream);

    for (int l = 0; l < NLAYER; l++) {
        prenorm_q_kernel<<<nodes, 64, 0, stream>>>(
            f0b, f1b, Wq0 + l * D0 * D0, Wq1 + l * D1 * D1, g0b, g1b, q0b, q1b);
        prep_kernel<<<16, 256, 0, stream>>>(
            Wk00 + l * D0 * D0, Wk10 + l * D1 * D0,
            Wk01 + l * D0 * D1, Wk11 + l * D1 * D1, Wk11r + l * D1 * D1,
            Wv00 + l * D0 * D0, Wv10 + l * D1 * D0,
            Wv01 + l * D0 * D1, Wv11 + l * D1 * D1, Wv11r + l * D1 * D1,
            Rw20 + l * RHD * D0, Rw21 + l * RHD * D1,
            B1H, B1L, B2H, B2L, R0H, R0L, R1H, R1L);
        attn_fused_kernel<<<ETOT / 64, 128, 0, stream>>>(
            g0b, g1b, nbr, rhatb, distb, q0b, q1b,
            Rw1 + l * RHD, Rb1 + l * RHD,
            B1H, B1L, B2H, B2L, R0H, R0L, R1H, R1L,
            Wo0 + l * D0 * D0, Wo1 + l * D1 * D1,
            f0b, f1b);
        ffn_kernel<<<nodes, 256, 0, stream>>>(
            F0w1 + l * D0 * 256, F0w2 + l * 256 * D0,
            F1w1 + l * D1 * 64, F1w2 + l * 64 * D1,
            f0b, f1b);
    }

    concat_kernel<<<(nodes * (D0 + D13) + 255) / 256, 256, 0, stream>>>(f0b, f1b, out);
}